// Round 6
// baseline (922.242 us; speedup 1.0000x reference)
//
#include <hip/hip_runtime.h>
#include <hip/hip_bf16.h>
#include <hip/hip_fp16.h>
#include <stdint.h>

typedef __bf16 bf16_t;
typedef bf16_t bf16x8 __attribute__((ext_vector_type(8)));
typedef bf16_t bf16x4 __attribute__((ext_vector_type(4)));
typedef float f32x4 __attribute__((ext_vector_type(4)));

#define BM 128
#define BN 128
#define BK 64

// async global->LDS, 16B per lane. LDS dst is wave-uniform base + lane*16;
// the GLOBAL source may be arbitrary per-lane (used for the bank swizzle).
__device__ __forceinline__ void gload_lds16(const void* g, void* l) {
    __builtin_amdgcn_global_load_lds(
        (const __attribute__((address_space(1))) void*)(uintptr_t)g,
        (__attribute__((address_space(3))) void*)(uintptr_t)l,
        16, 0, 0);
}

// ---------------------------------------------------------------------------
// 128x128 body, BK=64 as TWO stacked BK=32 sub-tiles (r5: conflicts 4.3M->0).
// Each half uses the verified BK=32 swizzle: staging slot s of row r holds
// global chunk ((s-(r>>1))&3) (compensated on the per-lane global source),
// read at phys chunk ((hw+(r>>1))&3).
// EPI: 0 = plain bf16 row-major store           (gemm1 K|Q)
//      2 = f32 store / rs[row]                  (gemm3)
//      3 = exp+causal bf16 store + atomic row-sum into rs  (qk)
//      4 = bf16 transposed into Vt[b][d][s]     (gemm1 V)
// ---------------------------------------------------------------------------
template <int EPI>
__device__ __forceinline__ void gemm_body(
    bf16_t* __restrict__ As, bf16_t* __restrict__ Bs,
    const bf16_t* __restrict__ A, long lda,
    const bf16_t* __restrict__ B, long ldb,
    void* __restrict__ Cv, long ldc,
    int k0beg, int k1end, float scale, int m0, int n0,
    float* __restrict__ rs)
{
    const int tid = threadIdx.x;
    const int wid = tid >> 6, lane = tid & 63;
    const int wr = wid >> 1, wc = wid & 1;
    const int hw = lane >> 4, ln = lane & 15;

    const int row0 = tid >> 2;                       // 0..63
    const int jj = ((tid & 3) - (tid >> 3)) & 3;     // swizzle-compensated chunk
    const bf16_t* srcA0 = A + (size_t)(m0 + row0) * lda + jj * 8;
    const bf16_t* srcB0 = B + (size_t)(n0 + row0) * ldb + jj * 8;

    f32x4 acc[4][4] = {};

    for (int k0 = k0beg; k0 < k1end; k0 += BK) {
#pragma unroll
        for (int i = 0; i < 4; i++) {
            const size_t roff = (size_t)((i & 1) * 64);
            const int koff = k0 + (i >> 1) * 32;
            gload_lds16(srcA0 + roff * lda + koff, &As[i * 2048 + tid * 8]);
            gload_lds16(srcB0 + roff * ldb + koff, &Bs[i * 2048 + tid * 8]);
        }
        __syncthreads();

#pragma unroll
        for (int h = 0; h < 2; h++) {
            bf16x8 af[4], bfr[4];
#pragma unroll
            for (int t = 0; t < 4; t++) {
                const int r  = wr * 64 + t * 16 + ln;
                const int rb = wc * 64 + t * 16 + ln;
                af[t]  = *(const bf16x8*)&As[h * 4096 + r  * 32 + (((hw + (r  >> 1)) & 3) * 8)];
                bfr[t] = *(const bf16x8*)&Bs[h * 4096 + rb * 32 + (((hw + (rb >> 1)) & 3) * 8)];
            }
#pragma unroll
            for (int ti = 0; ti < 4; ti++)
#pragma unroll
                for (int tj = 0; tj < 4; tj++)
                    acc[ti][tj] = __builtin_amdgcn_mfma_f32_16x16x32_bf16(
                        af[ti], bfr[tj], acc[ti][tj], 0, 0, 0);
        }
        __syncthreads();
    }

    // epilogue: C/D layout col=lane&15, row=(lane>>4)*4+reg (m89-verified)
#pragma unroll
    for (int ti = 0; ti < 4; ti++) {
        const int rbase = m0 + wr * 64 + ti * 16 + hw * 4;
        f32x4 inv4;
        if (EPI == 2) {
            const float4 r4 = *(const float4*)&rs[rbase];
            inv4[0] = 1.0f / r4.x; inv4[1] = 1.0f / r4.y;
            inv4[2] = 1.0f / r4.z; inv4[3] = 1.0f / r4.w;
        }
        float part[4] = {0.f, 0.f, 0.f, 0.f};
#pragma unroll
        for (int tj = 0; tj < 4; tj++) {
            const int col = n0 + wc * 64 + tj * 16 + ln;
            if (EPI == 4) {
                // transposed bf16: 4 consecutive rows -> 8B contiguous in Vt
                const int bb = rbase >> 11;
                const int s  = rbase & 2047;
                const int d  = col - 2048;
                bf16x4 o;
#pragma unroll
                for (int rg = 0; rg < 4; rg++) o[rg] = (bf16_t)acc[ti][tj][rg];
                *(bf16x4*)&((bf16_t*)Cv)[(size_t)bb * 2097152 + (size_t)d * 2048 + s] = o;
            } else {
#pragma unroll
                for (int rg = 0; rg < 4; rg++) {
                    const size_t idx = (size_t)(rbase + rg) * ldc + col;
                    if (EPI == 0) {
                        ((bf16_t*)Cv)[idx] = (bf16_t)acc[ti][tj][rg];
                    } else if (EPI == 2) {
                        ((float*)Cv)[idx] = acc[ti][tj][rg] * inv4[rg];
                    } else {  // EPI 3: exp + causal mask + row-sum
                        const float e = (col <= rbase + rg)
                                      ? __expf(acc[ti][tj][rg] * scale) : 0.0f;
                        part[rg] += e;
                        ((bf16_t*)Cv)[idx] = (bf16_t)e;
                    }
                }
            }
        }
        if (EPI == 3) {
#pragma unroll
            for (int rg = 0; rg < 4; rg++) {
                float p = part[rg];
                p += __shfl_xor(p, 1, 64);
                p += __shfl_xor(p, 2, 64);
                p += __shfl_xor(p, 4, 64);
                p += __shfl_xor(p, 8, 64);
                if (ln == 0) atomicAdd(&rs[rbase + rg], p);
            }
        }
    }
}

// ---------------------------------------------------------------------------
// Cross-block gate primitives (r6). Device-scope release/acquire with L2
// writeback/invalidate (per-XCD L2s are not coherent — G16).
// ---------------------------------------------------------------------------
__device__ __forceinline__ void gate_signal(int* p) {
    __syncthreads();                       // all waves' stores issued (vmcnt drained)
    if (threadIdx.x == 0) {
        __threadfence();                   // agent fence: L2 writeback
        __hip_atomic_fetch_add(p, 1, __ATOMIC_RELEASE, __HIP_MEMORY_SCOPE_AGENT);
    }
}

__device__ __forceinline__ void gate_wait(int* p, int target) {
    if (threadIdx.x == 0) {
        while (__hip_atomic_load(p, __ATOMIC_ACQUIRE, __HIP_MEMORY_SCOPE_AGENT) < target)
            __builtin_amdgcn_s_sleep(8);
    }
    __syncthreads();
    __threadfence();                       // agent fence: invalidate stale lines
}

// ---------------------------------------------------------------------------
// MEGA kernel (r6): persistent blocks + dependency-gated dynamic tile pool.
// Pool order: cast(256) -> kq(1024) -> v(512) -> qk(544) -> pv(512) = 2848.
// Gates: gemm1 <- castdone==256; qk <- kqdone==1024; pv <- vdone==512 AND
// qkdone[b*16+strip]==strip+1 (per-strip; qk heavy-first so heavy pv gates
// open first). Deadlock-free for any block scheduling: cursor is monotone
// and all deps point backward, so the minimal unfinished tile is always
// runnable (induction bottoms at gate-free cast tiles).
// ctl layout (ints): [0]=cursor [1]=castdone [2]=kqdone [3]=vdone [4..67]=qkdone
// ---------------------------------------------------------------------------
#define T_CAST 256
#define T_KQ   1024
#define T_V    512
#define T_QK   544
#define T_PV   512
#define NTILES (T_CAST + T_KQ + T_V + T_QK + T_PV)

__global__ __launch_bounds__(256, 2) void mega(
    const float* __restrict__ x,
    const float* __restrict__ Wk, const float* __restrict__ Wq,
    const float* __restrict__ Wv,
    bf16_t* __restrict__ xb, bf16_t* __restrict__ Wb,
    bf16_t* __restrict__ QKVb, bf16_t* __restrict__ Vt,
    bf16_t* __restrict__ E, float* __restrict__ rowsum,
    int* __restrict__ ctl, float* __restrict__ out)
{
    __shared__ __align__(16) bf16_t As[BM * BK];
    __shared__ __align__(16) bf16_t Bs[BN * BK];
    __shared__ int sh_t;
    int* cursor = ctl;
    int* castd  = ctl + 1;
    int* kqd    = ctl + 2;
    int* vd     = ctl + 3;
    int* qkd    = ctl + 4;                 // 64 entries
    const int tid = threadIdx.x;

    for (;;) {
        __syncthreads();                   // protect sh_t / LDS reuse
        if (tid == 0)
            sh_t = __hip_atomic_fetch_add(cursor, 1, __ATOMIC_RELAXED,
                                          __HIP_MEMORY_SCOPE_AGENT);
        __syncthreads();
        const int t = sh_t;
        if (t >= NTILES) break;

        if (t < T_CAST) {
            // ---- cast slice: 44 units of {256 thr x float4}
            for (int i = 0; i < 44; i++) {
                const int unit = t * 44 + i;
                const float* src;
                bf16_t* dst;
                if (unit < 8192) {
                    const size_t ix = ((size_t)unit * 256 + tid) * 4;
                    src = x + ix; dst = xb + ix;
                } else {
                    const size_t j = ((size_t)(unit - 8192) * 256 + tid) * 4;
                    dst = Wb + j;
                    if (j < (size_t)1048576)      src = Wk + j;
                    else if (j < (size_t)2097152) src = Wq + (j - 1048576);
                    else                          src = Wv + (j - 2097152);
                }
                const float4 v = *(const float4*)src;
                bf16x4 o;
                o.x = (bf16_t)v.x; o.y = (bf16_t)v.y;
                o.z = (bf16_t)v.z; o.w = (bf16_t)v.w;
                *(bf16x4*)dst = o;
            }
            gate_signal(castd);
        } else if (t < T_CAST + T_KQ) {
            // ---- gemm1 K|Q tile (128x128), XCD-swizzled over 64x16
            gate_wait(castd, T_CAST);
            const int g = t - T_CAST;
            const int xcd = g & 7;
            const int j   = g >> 3;        // 0..127
            const int p   = j >> 6;        // 0..1
            const int w   = j & 63;
            const int mblk = xcd * 8 + (w >> 3);   // 0..63
            const int nblk = p * 8 + (w & 7);      // 0..15
            gemm_body<0>(As, Bs, xb, 1024, Wb, 1024, QKVb, 2048,
                         0, 1024, 1.0f, mblk * BM, nblk * BN, nullptr);
            gate_signal(kqd);
        } else if (t < T_CAST + T_KQ + T_V) {
            // ---- V-projection tile, transposed store into Vt
            gate_wait(castd, T_CAST);
            const int g = t - (T_CAST + T_KQ);
            const int xcd = g & 7;
            const int j   = g >> 3;        // 0..63
            const int mblk = xcd * 8 + (j >> 3);
            const int nblk = j & 7;
            gemm_body<4>(As, Bs, xb, 1024, Wb, 1024, Vt, 2048,
                         0, 1024, 1.0f, mblk * BM, 2048 + nblk * BN, nullptr);
            gate_signal(vd);
        } else if (t < T_CAST + T_KQ + T_V + T_QK) {
            // ---- qk tile: exp(scale*Q K^T) causal, heavy strips first
            gate_wait(kqd, T_KQ);
            const int q = t - (T_CAST + T_KQ + T_V);
            const int b = q & 3;
            int rem = q >> 2;              // 0..135
            int my = 15, nx = 0;
#pragma unroll
            for (int m = 15; m >= 0; --m) {
                if (rem < m + 1) { my = m; nx = rem; break; }
                rem -= m + 1;
            }
            const bf16_t* base = QKVb + (size_t)b * (2048L * 2048);
            gemm_body<3>(As, Bs,
                         base + 1024, 2048,    // Q
                         base, 2048,           // K
                         E + (size_t)b * (2048L * 2048), 2048,
                         0, 1024, 0.03125f, my * BM, nx * BN,
                         rowsum + b * 2048);
            gate_signal(&qkd[b * 16 + my]);
        } else {
            // ---- pv tile: (E Vt^T)/rowsum, tri-K, heavy strips first
            const int p = t - (T_CAST + T_KQ + T_V + T_QK);
            const int strip = 15 - (p >> 5);
            const int nx = (p >> 2) & 7;
            const int b = p & 3;
            gate_wait(vd, T_V);
            gate_wait(&qkd[b * 16 + strip], strip + 1);
            const int m0 = strip * BM;
            gemm_body<2>(As, Bs,
                         E + (size_t)b * (2048L * 2048), 2048,
                         Vt + (size_t)b * (1024L * 2048), 2048,
                         out + (size_t)b * (2048L * 1024), 1024,
                         0, m0 + BM, 1.0f, m0, nx * BN,
                         rowsum + b * 2048);
        }
    }
}

// ======================= fallback path (small ws) ==========================
__global__ __launch_bounds__(256) void cast_all(
    const float* __restrict__ x,
    const float* __restrict__ Wk, const float* __restrict__ Wq,
    const float* __restrict__ Wv,
    bf16_t* __restrict__ xb, bf16_t* __restrict__ Wb,
    float* __restrict__ rowsum)
{
    const int blk = blockIdx.x;
    if (blk >= 11264) {
        const size_t i = ((size_t)(blk - 11264) * 256 + threadIdx.x) * 4;
        *(float4*)(rowsum + i) = make_float4(0.f, 0.f, 0.f, 0.f);
        return;
    }
    const float* src;
    bf16_t* dst;
    if (blk < 8192) {
        const size_t i = ((size_t)blk * 256 + threadIdx.x) * 4;
        src = x + i;
        dst = xb + i;
    } else {
        const size_t j = ((size_t)(blk - 8192) * 256 + threadIdx.x) * 4;
        dst = Wb + j;
        if (j < (size_t)1048576)      src = Wk + j;
        else if (j < (size_t)2097152) src = Wq + (j - 1048576);
        else                          src = Wv + (j - 2097152);
    }
    const float4 v = *(const float4*)src;
    bf16x4 o;
    o.x = (bf16_t)v.x; o.y = (bf16_t)v.y; o.z = (bf16_t)v.z; o.w = (bf16_t)v.w;
    *(bf16x4*)dst = o;
}

__global__ __launch_bounds__(256) void gemm1_kq128(
    const bf16_t* __restrict__ xb, const bf16_t* __restrict__ Wb,
    bf16_t* __restrict__ QKVb)
{
    __shared__ __align__(16) bf16_t As[BM * BK];
    __shared__ __align__(16) bf16_t Bs[BN * BK];
    const int g = blockIdx.x;              // 0..1023
    const int xcd = g & 7;
    const int j   = g >> 3;
    const int p   = j >> 6;
    const int w   = j & 63;
    const int mblk = xcd * 8 + (w >> 3);
    const int nblk = p * 8 + (w & 7);
    gemm_body<0>(As, Bs, xb, 1024, Wb, 1024, QKVb, 2048,
                 0, 1024, 1.0f, mblk * BM, nblk * BN, nullptr);
}

__global__ __launch_bounds__(256) void gemm1_v(
    const bf16_t* __restrict__ xb, const bf16_t* __restrict__ Wb,
    bf16_t* __restrict__ Vt)
{
    __shared__ __align__(16) bf16_t As[BM * BK];
    __shared__ __align__(16) bf16_t Bs[BN * BK];
    const int lin = blockIdx.x;
    const int xcd = lin & 7;
    const int j   = lin >> 3;
    const int mblk = xcd * 8 + (j >> 3);
    const int nblk = j & 7;
    gemm_body<4>(As, Bs, xb, 1024, Wb, 1024, Vt, 2048,
                 0, 1024, 1.0f, mblk * BM, 2048 + nblk * BN, nullptr);
}

__global__ __launch_bounds__(256) void qk_gemm(
    const bf16_t* __restrict__ QKVb, bf16_t* __restrict__ E,
    float* __restrict__ rowsum)
{
    __shared__ __align__(16) bf16_t As[BM * BK];
    __shared__ __align__(16) bf16_t Bs[BN * BK];
    const int b = blockIdx.x & 3;
    int rem = blockIdx.x >> 2;
    int my = 15, nx = 0;
#pragma unroll
    for (int m = 15; m >= 0; --m) {
        if (rem < m + 1) { my = m; nx = rem; break; }
        rem -= m + 1;
    }
    const bf16_t* base = QKVb + (size_t)b * (2048L * 2048);
    gemm_body<3>(As, Bs,
                 base + 1024, 2048,
                 base, 2048,
                 E + (size_t)b * (2048L * 2048), 2048,
                 0, 1024, 0.03125f, my * BM, nx * BN,
                 rowsum + b * 2048);
}

__global__ __launch_bounds__(256) void gemm3_pv(
    const bf16_t* __restrict__ E, const bf16_t* __restrict__ Vt,
    const float* __restrict__ rowsum, float* __restrict__ out)
{
    __shared__ __align__(16) bf16_t As[BM * BK];
    __shared__ __align__(16) bf16_t Bs[BN * BK];
    const int id = blockIdx.x;
    const int strip = 15 - (id >> 5);
    const int nx = (id >> 2) & 7;
    const int b = id & 3;
    const int m0 = strip * BM;
    gemm_body<2>(As, Bs,
                 E + (size_t)b * (2048L * 2048), 2048,
                 Vt + (size_t)b * (1024L * 2048), 2048,
                 out + (size_t)b * (2048L * 1024), 1024,
                 0, m0 + BM, 1.0f, m0, nx * BN,
                 (float*)rowsum + b * 2048);
}

// ---------------------------------------------------------------------------
extern "C" void kernel_launch(void* const* d_in, const int* in_sizes, int n_in,
                              void* d_out, int out_size, void* d_ws, size_t ws_size,
                              hipStream_t stream)
{
    const float* x  = (const float*)d_in[0];
    const float* Wk = (const float*)d_in[1];
    const float* Wq = (const float*)d_in[2];
    const float* Wv = (const float*)d_in[3];
    char* ws = (char*)d_ws;

    // ws layout (big path):
    //   [0,32)    QKVb bf16 8192x2048  ([K|Q] columns; V goes to Vt)
    //   [32,48)   Vt   bf16 4 x 1024x2048 (written transposed)
    //   [48,64)   xb   bf16 8192x1024
    //   [64,70)   Wb   bf16 3072x1024
    //   [72,105.6) E   bf16 4 x 2048x2048 (non-aliased)
    //   [106,106+32K) rowsum f32 4x2048; then ctl (68 ints) — both memset'd
    bf16_t* QKVb = (bf16_t*)(ws);
    bf16_t* Vt   = (bf16_t*)(ws + ((size_t)32 << 20));
    bf16_t* xb   = (bf16_t*)(ws + ((size_t)48 << 20));
    bf16_t* Wb   = (bf16_t*)(ws + ((size_t)64 << 20));
    const bool big = ws_size >= ((size_t)107 << 20);
    bf16_t* E      = (bf16_t*)(ws + ((size_t)(big ? 72 : 48) << 20));
    float*  rowsum = (float*)(ws + ((size_t)(big ? 106 : 80) << 20));
    int*    ctl    = (int*)(ws + ((size_t)106 << 20) + 32768);
    float*  out    = (float*)d_out;

    if (big) {
        // zero rowsum (32 KB) + ctl (cursor/castdone/kqdone/vdone/qkdone[64])
        hipMemsetAsync(ws + ((size_t)106 << 20), 0, 32768 + 4096, stream);
        mega<<<512, 256, 0, stream>>>(x, Wk, Wq, Wv, xb, Wb, QKVb, Vt, E,
                                      rowsum, ctl, out);
    } else {
        cast_all<<<11272, 256, 0, stream>>>(x, Wk, Wq, Wv, xb, Wb, rowsum);
        gemm1_kq128<<<1024, 256, 0, stream>>>(xb, Wb, QKVb);
        gemm1_v<<<512, 256, 0, stream>>>(xb, Wb, Vt);
        qk_gemm<<<544, 256, 0, stream>>>(QKVb, E, rowsum);
        gemm3_pv<<<512, 256, 0, stream>>>(E, Vt, rowsum, out);
    }
}

// Round 7
// 222.094 us; speedup vs baseline: 4.1525x; 4.1525x over previous
//
#include <hip/hip_runtime.h>
#include <hip/hip_bf16.h>
#include <hip/hip_fp16.h>
#include <stdint.h>

typedef __bf16 bf16_t;
typedef bf16_t bf16x8 __attribute__((ext_vector_type(8)));
typedef bf16_t bf16x4 __attribute__((ext_vector_type(4)));
typedef float f32x4 __attribute__((ext_vector_type(4)));

#define BM 128
#define BN 128
#define BK 64

// async global->LDS, 16B per lane. LDS dst is wave-uniform base + lane*16;
// the GLOBAL source may be arbitrary per-lane (used for the bank swizzle).
__device__ __forceinline__ void gload_lds16(const void* g, void* l) {
    __builtin_amdgcn_global_load_lds(
        (const __attribute__((address_space(1))) void*)(uintptr_t)g,
        (__attribute__((address_space(3))) void*)(uintptr_t)l,
        16, 0, 0);
}

// ---------------------------------------------------------------------------
// 128x128 body, BK=64 as TWO stacked BK=32 sub-tiles (r5: conflicts 4.3M->0).
// Each half uses the verified BK=32 swizzle: staging slot s of row r holds
// global chunk ((s-(r>>1))&3) (compensated on the per-lane global source),
// read at phys chunk ((hw+(r>>1))&3).
// EPI: 2 = f32 store / rs[row]                  (gemm3)
//      3 = exp+causal bf16 store + atomic row-sum into rs  (qk)
//      4 = bf16 transposed into Vt[b][d][s]     (gemm1 V)
// NOTE r6: persistent-mega variant with per-tile agent fences caused an L2
// invalidation storm (FETCH 60->344 MB, 4.4% MfmaUtil, 922 us). Reverted to
// the 4-dispatch structure; do not re-introduce device-scope gates per tile.
// ---------------------------------------------------------------------------
template <int EPI>
__device__ __forceinline__ void gemm_body(
    bf16_t* __restrict__ As, bf16_t* __restrict__ Bs,
    const bf16_t* __restrict__ A, long lda,
    const bf16_t* __restrict__ B, long ldb,
    void* __restrict__ Cv, long ldc,
    int k0beg, int k1end, float scale, int m0, int n0,
    float* __restrict__ rs)
{
    const int tid = threadIdx.x;
    const int wid = tid >> 6, lane = tid & 63;
    const int wr = wid >> 1, wc = wid & 1;
    const int hw = lane >> 4, ln = lane & 15;

    const int row0 = tid >> 2;                       // 0..63
    const int jj = ((tid & 3) - (tid >> 3)) & 3;     // swizzle-compensated chunk
    const bf16_t* srcA0 = A + (size_t)(m0 + row0) * lda + jj * 8;
    const bf16_t* srcB0 = B + (size_t)(n0 + row0) * ldb + jj * 8;

    f32x4 acc[4][4] = {};

    for (int k0 = k0beg; k0 < k1end; k0 += BK) {
#pragma unroll
        for (int i = 0; i < 4; i++) {
            const size_t roff = (size_t)((i & 1) * 64);
            const int koff = k0 + (i >> 1) * 32;
            gload_lds16(srcA0 + roff * lda + koff, &As[i * 2048 + tid * 8]);
            gload_lds16(srcB0 + roff * ldb + koff, &Bs[i * 2048 + tid * 8]);
        }
        __syncthreads();

#pragma unroll
        for (int h = 0; h < 2; h++) {
            bf16x8 af[4], bfr[4];
#pragma unroll
            for (int t = 0; t < 4; t++) {
                const int r  = wr * 64 + t * 16 + ln;
                const int rb = wc * 64 + t * 16 + ln;
                af[t]  = *(const bf16x8*)&As[h * 4096 + r  * 32 + (((hw + (r  >> 1)) & 3) * 8)];
                bfr[t] = *(const bf16x8*)&Bs[h * 4096 + rb * 32 + (((hw + (rb >> 1)) & 3) * 8)];
            }
#pragma unroll
            for (int ti = 0; ti < 4; ti++)
#pragma unroll
                for (int tj = 0; tj < 4; tj++)
                    acc[ti][tj] = __builtin_amdgcn_mfma_f32_16x16x32_bf16(
                        af[ti], bfr[tj], acc[ti][tj], 0, 0, 0);
        }
        __syncthreads();
    }

    // epilogue: C/D layout col=lane&15, row=(lane>>4)*4+reg (m89-verified)
#pragma unroll
    for (int ti = 0; ti < 4; ti++) {
        const int rbase = m0 + wr * 64 + ti * 16 + hw * 4;
        f32x4 inv4;
        if (EPI == 2) {
            const float4 r4 = *(const float4*)&rs[rbase];
            inv4[0] = 1.0f / r4.x; inv4[1] = 1.0f / r4.y;
            inv4[2] = 1.0f / r4.z; inv4[3] = 1.0f / r4.w;
        }
        float part[4] = {0.f, 0.f, 0.f, 0.f};
#pragma unroll
        for (int tj = 0; tj < 4; tj++) {
            const int col = n0 + wc * 64 + tj * 16 + ln;
            if (EPI == 4) {
                // transposed bf16: 4 consecutive rows -> 8B contiguous in Vt
                const int bb = rbase >> 11;
                const int s  = rbase & 2047;
                const int d  = col - 2048;
                bf16x4 o;
#pragma unroll
                for (int rg = 0; rg < 4; rg++) o[rg] = (bf16_t)acc[ti][tj][rg];
                *(bf16x4*)&((bf16_t*)Cv)[(size_t)bb * 2097152 + (size_t)d * 2048 + s] = o;
            } else {
#pragma unroll
                for (int rg = 0; rg < 4; rg++) {
                    const size_t idx = (size_t)(rbase + rg) * ldc + col;
                    if (EPI == 2) {
                        ((float*)Cv)[idx] = acc[ti][tj][rg] * inv4[rg];
                    } else {  // EPI 3: exp + causal mask + row-sum
                        const float e = (col <= rbase + rg)
                                      ? __expf(acc[ti][tj][rg] * scale) : 0.0f;
                        part[rg] += e;
                        ((bf16_t*)Cv)[idx] = (bf16_t)e;
                    }
                }
            }
        }
        if (EPI == 3) {
#pragma unroll
            for (int rg = 0; rg < 4; rg++) {
                float p = part[rg];
                p += __shfl_xor(p, 1, 64);
                p += __shfl_xor(p, 2, 64);
                p += __shfl_xor(p, 4, 64);
                p += __shfl_xor(p, 8, 64);
                if (ln == 0) atomicAdd(&rs[rbase + rg], p);
            }
        }
    }
}

// ---------------------------------------------------------------------------
// 256x256 8-phase body for gemm1 K|Q (r3: ~parity at K=1024; kept).
// ---------------------------------------------------------------------------
__device__ __forceinline__ void gemm256_body(
    bf16_t* __restrict__ lds,
    const bf16_t* __restrict__ A, long lda,
    const bf16_t* __restrict__ B, long ldb,
    bf16_t* __restrict__ C, long ldc,
    int nt, int m0, int n0)
{
    const int tid = threadIdx.x;
    const int wid = tid >> 6, lane = tid & 63;
    const int wr = wid >> 2, wcn = wid & 3;
    const int hw = lane >> 4, ln = lane & 15;

    const int srow = (wid << 3) + (lane >> 3);          // 0..63
    const int clog = ((lane & 7) - (lane >> 3)) & 7;    // swizzle-compensated chunk
    const bf16_t* sA = A + (size_t)(m0 + srow) * lda + clog * 8;
    const bf16_t* sB = B + (size_t)(n0 + srow) * ldb + clog * 8;
    char* ldsc = (char*)lds;
    const int wb = wid << 10;

#define STG_A(bf, q, kt) gload_lds16(sA + (size_t)(q) * 64 * lda + (size_t)(kt) * 64, \
                                     ldsc + (bf) * 65536 + (q) * 8192 + wb)
#define STG_B(bf, q, kt) gload_lds16(sB + (size_t)(q) * 64 * ldb + (size_t)(kt) * 64, \
                                     ldsc + (bf) * 65536 + 32768 + (q) * 8192 + wb)

    const int c0 = ((hw + ln) & 7) << 4;
    const int c1 = ((hw + ln + 4) & 7) << 4;
    const int aR = (wr * 128 + ln) * 128;
    const int bR = 32768 + (wcn * 64 + ln) * 128;

#define RDA(bf, fr, ks) (*(const bf16x8*)(ldsc + (bf) * 65536 + aR + (fr) * 2048 + ((ks) ? c1 : c0)))
#define RDB(bf, fc, ks) (*(const bf16x8*)(ldsc + (bf) * 65536 + bR + (fc) * 2048 + ((ks) ? c1 : c0)))

    f32x4 acc[8][4] = {};

    STG_A(0, 0, 0); STG_A(0, 2, 0); STG_B(0, 0, 0); STG_B(0, 1, 0);
    STG_A(0, 1, 0); STG_A(0, 3, 0); STG_B(0, 2, 0); STG_B(0, 3, 0);
    STG_A(1, 0, 1); STG_A(1, 2, 1); STG_B(1, 0, 1); STG_B(1, 1, 1);
    STG_A(1, 1, 1); STG_A(1, 3, 1);
    asm volatile("s_waitcnt vmcnt(6)" ::: "memory");
    __builtin_amdgcn_s_barrier();

    for (int t = 0; t < nt; ++t) {
        const int bc = t & 1, bn = bc ^ 1;
        const int kt1 = (t + 1) & (nt - 1);
        const int kt2 = (t + 2) & (nt - 1);
        bf16x8 af[4][2], bl[2][2], bh[2][2];

        // ---- P1
#pragma unroll
        for (int fr = 0; fr < 4; ++fr) {
            af[fr][0] = RDA(bc, fr, 0);
            af[fr][1] = RDA(bc, fr, 1);
        }
#pragma unroll
        for (int fc = 0; fc < 2; ++fc) {
            bl[fc][0] = RDB(bc, fc, 0);
            bl[fc][1] = RDB(bc, fc, 1);
        }
        STG_B(bn, 2, kt1); STG_B(bn, 3, kt1);
        __builtin_amdgcn_s_barrier();
        asm volatile("s_waitcnt lgkmcnt(0)" ::: "memory");
        __builtin_amdgcn_sched_barrier(0);
        __builtin_amdgcn_s_setprio(1);
#pragma unroll
        for (int fr = 0; fr < 4; ++fr)
#pragma unroll
            for (int fc = 0; fc < 2; ++fc)
#pragma unroll
                for (int ks = 0; ks < 2; ++ks)
                    acc[fr][fc] = __builtin_amdgcn_mfma_f32_16x16x32_bf16(
                        af[fr][ks], bl[fc][ks], acc[fr][fc], 0, 0, 0);
        __builtin_amdgcn_s_setprio(0);
        __builtin_amdgcn_s_barrier();

        // ---- P2
#pragma unroll
        for (int fc = 0; fc < 2; ++fc) {
            bh[fc][0] = RDB(bc, fc + 2, 0);
            bh[fc][1] = RDB(bc, fc + 2, 1);
        }
        STG_A(bc, 0, kt2); STG_A(bc, 2, kt2);
        __builtin_amdgcn_s_barrier();
        asm volatile("s_waitcnt lgkmcnt(0)" ::: "memory");
        __builtin_amdgcn_sched_barrier(0);
        __builtin_amdgcn_s_setprio(1);
#pragma unroll
        for (int fr = 0; fr < 4; ++fr)
#pragma unroll
            for (int fc = 0; fc < 2; ++fc)
#pragma unroll
                for (int ks = 0; ks < 2; ++ks)
                    acc[fr][fc + 2] = __builtin_amdgcn_mfma_f32_16x16x32_bf16(
                        af[fr][ks], bh[fc][ks], acc[fr][fc + 2], 0, 0, 0);
        __builtin_amdgcn_s_setprio(0);
        __builtin_amdgcn_s_barrier();

        // ---- P3
#pragma unroll
        for (int fr = 0; fr < 4; ++fr) {
            af[fr][0] = RDA(bc, fr + 4, 0);
            af[fr][1] = RDA(bc, fr + 4, 1);
        }
        STG_B(bc, 0, kt2); STG_B(bc, 1, kt2);
        __builtin_amdgcn_s_barrier();
        asm volatile("s_waitcnt lgkmcnt(0)" ::: "memory");
        __builtin_amdgcn_sched_barrier(0);
        __builtin_amdgcn_s_setprio(1);
#pragma unroll
        for (int fr = 0; fr < 4; ++fr)
#pragma unroll
            for (int fc = 0; fc < 2; ++fc)
#pragma unroll
                for (int ks = 0; ks < 2; ++ks)
                    acc[fr + 4][fc + 2] = __builtin_amdgcn_mfma_f32_16x16x32_bf16(
                        af[fr][ks], bh[fc][ks], acc[fr + 4][fc + 2], 0, 0, 0);
        __builtin_amdgcn_s_setprio(0);
        __builtin_amdgcn_s_barrier();

        // ---- P4
        STG_A(bc, 1, kt2); STG_A(bc, 3, kt2);
        __builtin_amdgcn_s_setprio(1);
#pragma unroll
        for (int fr = 0; fr < 4; ++fr)
#pragma unroll
            for (int fc = 0; fc < 2; ++fc)
#pragma unroll
                for (int ks = 0; ks < 2; ++ks)
                    acc[fr + 4][fc] = __builtin_amdgcn_mfma_f32_16x16x32_bf16(
                        af[fr][ks], bl[fc][ks], acc[fr + 4][fc], 0, 0, 0);
        __builtin_amdgcn_s_setprio(0);
        asm volatile("s_waitcnt vmcnt(6)" ::: "memory");
        __builtin_amdgcn_s_barrier();
    }

    asm volatile("s_waitcnt vmcnt(0)" ::: "memory");

#pragma unroll
    for (int fr = 0; fr < 8; ++fr) {
        const int rbase = m0 + wr * 128 + fr * 16 + hw * 4;
#pragma unroll
        for (int fc = 0; fc < 4; ++fc) {
            const int col = n0 + wcn * 64 + fc * 16 + ln;
#pragma unroll
            for (int rg = 0; rg < 4; rg++)
                C[(size_t)(rbase + rg) * ldc + col] = (bf16_t)acc[fr][fc][rg];
        }
    }
#undef STG_A
#undef STG_B
#undef RDA
#undef RDB
}

// ---------------------------------------------------------------------------
// GEMM1a: [K|Q] = x*W^T row-major into QKVb (8192x2048). grid exactly 256.
// ---------------------------------------------------------------------------
__global__ __launch_bounds__(512, 2) void gemm1_kq(
    const bf16_t* __restrict__ xb, const bf16_t* __restrict__ Wb,
    bf16_t* __restrict__ QKVb)
{
    __shared__ __align__(16) bf16_t lds[65536];   // 128 KiB
    const int lin = blockIdx.x;                   // 0..255
    const int xcd = lin & 7;
    const int j   = lin >> 3;                     // 0..31
    const int mblk = xcd * 4 + (j & 3);           // 0..31
    const int nblk = j >> 2;                      // 0..7
    gemm256_body(lds, xb, 1024, Wb, 1024, QKVb, 2048, 16, mblk * 256, nblk * 256);
}

// ---------------------------------------------------------------------------
// FUSED V-projection + QK-exp: independent once kq is done. ids [0,512)=V,
// [512,1056)=QK.
// ---------------------------------------------------------------------------
__global__ __launch_bounds__(256) void vqk_fused(
    const bf16_t* __restrict__ xb, const bf16_t* __restrict__ Wb,
    bf16_t* __restrict__ Vt,
    const bf16_t* __restrict__ QKVb, bf16_t* __restrict__ E,
    float* __restrict__ rowsum)
{
    __shared__ __align__(16) bf16_t As[BM * BK];
    __shared__ __align__(16) bf16_t Bs[BN * BK];
    const int id = blockIdx.x;
    if (id < 512) {
        const int xcd = id & 7;
        const int j   = id >> 3;               // 0..63
        const int mblk = xcd * 8 + (j >> 3);   // 0..63
        const int nblk = j & 7;                // 0..7
        gemm_body<4>(As, Bs, xb, 1024, Wb, 1024, Vt, 2048,
                     0, 1024, 1.0f, mblk * BM, 2048 + nblk * BN, nullptr);
    } else {
        const int qid = id - 512;              // 0..543
        const int b = qid & 3;
        int rem = qid >> 2;                    // 0..135
        int my = 15, nx = 0;
#pragma unroll
        for (int m = 15; m >= 0; --m) {        // heavy strips first
            if (rem < m + 1) { my = m; nx = rem; break; }
            rem -= m + 1;
        }
        const bf16_t* base = QKVb + (size_t)b * (2048L * 2048);
        gemm_body<3>(As, Bs,
                     base + 1024, 2048,        // Q
                     base, 2048,               // K
                     E + (size_t)b * (2048L * 2048), 2048,
                     0, 1024, 0.03125f, my * BM, nx * BN,
                     rowsum + b * 2048);
    }
}

// --------------------- fallback serial pair (small ws) ---------------------
__global__ __launch_bounds__(256) void gemm1_v(
    const bf16_t* __restrict__ xb, const bf16_t* __restrict__ Wb,
    bf16_t* __restrict__ Vt)
{
    __shared__ __align__(16) bf16_t As[BM * BK];
    __shared__ __align__(16) bf16_t Bs[BN * BK];
    const int lin = blockIdx.x;
    const int xcd = lin & 7;
    const int j   = lin >> 3;
    const int mblk = xcd * 8 + (j >> 3);
    const int nblk = j & 7;
    gemm_body<4>(As, Bs, xb, 1024, Wb, 1024, Vt, 2048,
                 0, 1024, 1.0f, mblk * BM, 2048 + nblk * BN, nullptr);
}

__global__ __launch_bounds__(256) void qk_gemm(
    const bf16_t* __restrict__ QKVb, bf16_t* __restrict__ E,
    float* __restrict__ rowsum)
{
    __shared__ __align__(16) bf16_t As[BM * BK];
    __shared__ __align__(16) bf16_t Bs[BN * BK];
    const int b = blockIdx.x & 3;
    int rem = blockIdx.x >> 2;
    int my = 15, nx = 0;
#pragma unroll
    for (int m = 15; m >= 0; --m) {
        if (rem < m + 1) { my = m; nx = rem; break; }
        rem -= m + 1;
    }
    const bf16_t* base = QKVb + (size_t)b * (2048L * 2048);
    gemm_body<3>(As, Bs,
                 base + 1024, 2048,
                 base, 2048,
                 E + (size_t)b * (2048L * 2048), 2048,
                 0, 1024, 0.03125f, my * BM, nx * BN,
                 rowsum + b * 2048);
}

// ---------------------------------------------------------------------------
// GEMM3: out = (E * Vt^T) / rowsum per batch -> f32. tri-K (Keff=m0+128).
// r7: COMPLEMENTARY-PAIR ordering. At 2 blocks/CU, CU i receives blocks
// {i, i+256}; the old heavy-first order paired strips (15-g, 7-g) -> per-CU
// load 20..48 k-steps (2.4x imbalance, makespan 48). Now first half carries
// strips 15..8, second half strips 0..7 so the pair is (s, 15-s) -> uniform
// 34 k-steps/CU (makespan 48 -> 34).
// ---------------------------------------------------------------------------
__global__ __launch_bounds__(256) void gemm3_pv(
    const bf16_t* __restrict__ E, const bf16_t* __restrict__ Vt,
    const float* __restrict__ rowsum, float* __restrict__ out)
{
    __shared__ __align__(16) bf16_t As[BM * BK];
    __shared__ __align__(16) bf16_t Bs[BN * BK];
    const int id = blockIdx.x;             // 0..511
    const int strip = (id < 256) ? (15 - (id >> 5)) : ((id - 256) >> 5);
    const int nx = (id >> 2) & 7;
    const int b = id & 3;
    const int m0 = strip * BM;
    gemm_body<2>(As, Bs,
                 E + (size_t)b * (2048L * 2048), 2048,
                 Vt + (size_t)b * (1024L * 2048), 2048,
                 out + (size_t)b * (2048L * 1024), 1024,
                 0, m0 + BM, 1.0f, m0, nx * BN,
                 (float*)rowsum + b * 2048);
}

// ---------------------------------------------------------------------------
// Merged input casts: blocks [0,8192) cast x, [8192,11264) cast W,
// [11264,11272) zero the rowsum array (4x2048 f32).
__global__ __launch_bounds__(256) void cast_all(
    const float* __restrict__ x,
    const float* __restrict__ Wk, const float* __restrict__ Wq,
    const float* __restrict__ Wv,
    bf16_t* __restrict__ xb, bf16_t* __restrict__ Wb,
    float* __restrict__ rowsum)
{
    const int blk = blockIdx.x;
    if (blk >= 11264) {
        const size_t i = ((size_t)(blk - 11264) * 256 + threadIdx.x) * 4;
        *(float4*)(rowsum + i) = make_float4(0.f, 0.f, 0.f, 0.f);
        return;
    }
    const float* src;
    bf16_t* dst;
    if (blk < 8192) {
        const size_t i = ((size_t)blk * 256 + threadIdx.x) * 4;
        src = x + i;
        dst = xb + i;
    } else {
        const size_t j = ((size_t)(blk - 8192) * 256 + threadIdx.x) * 4;
        dst = Wb + j;
        if (j < (size_t)1048576)      src = Wk + j;
        else if (j < (size_t)2097152) src = Wq + (j - 1048576);
        else                          src = Wv + (j - 2097152);
    }
    const float4 v = *(const float4*)src;
    bf16x4 o;
    o.x = (bf16_t)v.x; o.y = (bf16_t)v.y; o.z = (bf16_t)v.z; o.w = (bf16_t)v.w;
    *(bf16x4*)dst = o;
}

// ---------------------------------------------------------------------------
extern "C" void kernel_launch(void* const* d_in, const int* in_sizes, int n_in,
                              void* d_out, int out_size, void* d_ws, size_t ws_size,
                              hipStream_t stream)
{
    const float* x  = (const float*)d_in[0];
    const float* Wk = (const float*)d_in[1];
    const float* Wq = (const float*)d_in[2];
    const float* Wv = (const float*)d_in[3];
    char* ws = (char*)d_ws;

    // ws layout:
    //   [0,32)    QKVb bf16 8192x2048  ([K|Q] columns; V goes to Vt)
    //   [32,48)   Vt   bf16 4 x 1024x2048 (written transposed)
    //   [48,64)   xb   bf16 8192x1024
    //   [64,70)   Wb   bf16 3072x1024
    // big-ws (>=107 MB): E at [72,105.6) NON-ALIASED (enables v+qk fusion),
    //   rowsum at [106,...). small-ws fallback: E aliases xb+Wb at [48,80),
    //   rowsum at [80,...), v/qk serialized.
    bf16_t* QKVb = (bf16_t*)(ws);
    bf16_t* Vt   = (bf16_t*)(ws + ((size_t)32 << 20));
    bf16_t* xb   = (bf16_t*)(ws + ((size_t)48 << 20));
    bf16_t* Wb   = (bf16_t*)(ws + ((size_t)64 << 20));
    const bool big = ws_size >= ((size_t)107 << 20);
    bf16_t* E      = (bf16_t*)(ws + ((size_t)(big ? 72 : 48) << 20));
    float*  rowsum = (float*)(ws + ((size_t)(big ? 106 : 80) << 20));
    float*  out    = (float*)d_out;

    // 1. cast inputs to bf16 + zero rowsum
    cast_all<<<11272, 256, 0, stream>>>(x, Wk, Wq, Wv, xb, Wb, rowsum);

    // 2. GEMM1 K|Q
    gemm1_kq<<<256, 512, 0, stream>>>(xb, Wb, QKVb);

    // 3. V-projection + causal exp(QK^T) fused (or serial fallback)
    if (big) {
        vqk_fused<<<1056, 256, 0, stream>>>(xb, Wb, Vt, QKVb, E, rowsum);
    } else {
        gemm1_v<<<512, 256, 0, stream>>>(xb, Wb, Vt);
        qk_gemm<<<544, 256, 0, stream>>>(QKVb, E, rowsum);
    }

    // 4. GEMM3: out = (E Vt^T)/rowsum, complementary-pair balanced
    gemm3_pv<<<512, 256, 0, stream>>>(E, Vt, rowsum, out);
}